// Round 5
// baseline (211.902 us; speedup 1.0000x reference)
//
#include <hip/hip_runtime.h>
#include <hip/hip_bf16.h>
#include <math.h>

#define BATCH 4
#define SEQ   4096
#define EMB   1024
#define HD    64
#define SCALE 0.03125f   // EMB^-0.5 = 1/32, exact in bf16

typedef __attribute__((ext_vector_type(8))) short short8;  // 8 bf16 = 4 VGPRs
typedef __attribute__((ext_vector_type(4))) float f32x4;

__device__ __forceinline__ short8 ld8g(const __hip_bfloat16* p) {
    union { uint4 u; short8 s; } cv;
    cv.u = *(const uint4*)p;          // 16B aligned by construction
    return cv.s;
}
__device__ __forceinline__ short8 ld8l(const unsigned int* p) {
    union { uint4 u; short8 s; } cv;
    cv.u = *(const uint4*)p;
    return cv.s;
}
__device__ __forceinline__ unsigned short bfb(float a) {
    union { __hip_bfloat16 h; unsigned short u; } cv;
    cv.h = __hip_bfloat16(a);
    return cv.u;
}

// ---------------------------------------------------------------------------
// prep_w: W{q,k,v} fp32 [1024][64] -> WT bf16 [192][1024]  (unchanged)
// ---------------------------------------------------------------------------
__global__ __launch_bounds__(256) void prep_w(
    const float* __restrict__ Wk, const float* __restrict__ Wq,
    const float* __restrict__ Wv, __hip_bfloat16* __restrict__ WT)
{
    const int n = blockIdx.x;                 // 0..191
    const float* W = (n < 64) ? Wq : (n < 128) ? Wk : Wv;
    const int h = n & 63;
    const int t = threadIdx.x;
#pragma unroll
    for (int i = 0; i < 4; ++i) {
        const int k = i * 256 + t;
        WT[(size_t)n * EMB + k] = __hip_bfloat16(W[(size_t)k * HD + h]);
    }
}

// ---------------------------------------------------------------------------
// gemm_proj v2: [16384 x 1024] x [1024 x 192] via 16x16x32 bf16 MFMA.
// Wave = 16 rows x 96 cols (6 frags) x FULL K=1024 -> only 6 concurrent
// B-frags per step (R4's 12-frag version starved the allocator to 48 VGPRs
// and serialized every load). No LDS, no barrier; epilogue writes directly.
// Grid 512 blocks x 4 waves = 2 waves/SIMD, 2 blocks/CU.
// ---------------------------------------------------------------------------
__global__ __launch_bounds__(256, 2) void gemm_proj(
    const float* __restrict__ x,
    const __hip_bfloat16* __restrict__ WT,
    __hip_bfloat16* __restrict__ qs,
    __hip_bfloat16* __restrict__ kb,
    __hip_bfloat16* __restrict__ vT)
{
    const int tid  = threadIdx.x;
    const int lane = tid & 63;
    const int c    = lane & 15;
    const int quad = lane >> 4;
    const int w    = tid >> 6;                // 0..3
    const int rw   = w & 1;                   // row sub-tile (16 rows)
    const int nh   = w >> 1;                  // col half (96 cols)
    const int R0   = blockIdx.x * 32;
    const int arow = R0 + rw * 16 + c;        // A-operand row for this lane

    f32x4 acc[6];
#pragma unroll
    for (int f = 0; f < 6; ++f) acc[f] = (f32x4){0.f, 0.f, 0.f, 0.f};

    const float* xp = x + (size_t)arow * EMB + quad * 8;
    const __hip_bfloat16* wp = WT + (size_t)(nh * 96 + c) * EMB + quad * 8;

#pragma unroll 4
    for (int s = 0; s < 32; ++s) {            // 32 K-steps of 32
        const float4 xa = *(const float4*)(xp + s * 32);
        const float4 xb = *(const float4*)(xp + s * 32 + 4);
        union { unsigned short u[8]; short8 s8; } av;
        av.u[0] = bfb(xa.x); av.u[1] = bfb(xa.y);
        av.u[2] = bfb(xa.z); av.u[3] = bfb(xa.w);
        av.u[4] = bfb(xb.x); av.u[5] = bfb(xb.y);
        av.u[6] = bfb(xb.z); av.u[7] = bfb(xb.w);
#pragma unroll
        for (int f = 0; f < 6; ++f) {
            const short8 bf = ld8g(wp + (size_t)f * 16 * EMB + s * 32);
            acc[f] = __builtin_amdgcn_mfma_f32_16x16x32_bf16(av.s8, bf, acc[f], 0, 0, 0);
        }
    }

    // ---- epilogue: D[m = quad*4+r][n = nh*96 + f*16 + c], direct stores ----
#pragma unroll
    for (int f = 0; f < 6; ++f) {
#pragma unroll
        for (int r = 0; r < 4; ++r) {
            const int m = R0 + rw * 16 + quad * 4 + r;   // global row
            const int n = nh * 96 + f * 16 + c;          // 0..191
            const float val = acc[f][r];
            if (n < 64) {
                qs[(size_t)m * HD + n] = __hip_bfloat16(val * SCALE);
            } else if (n < 128) {
                kb[(size_t)m * HD + (n - 64)] = __hip_bfloat16(val);
            } else {
                const int b  = m >> 12;
                const int sq = m & (SEQ - 1);
                const int sp = (sq & ~63) | ((sq & 15) << 2) | ((sq >> 4) & 3);
                vT[((size_t)b * HD + (n - 128)) * SEQ + sp] = __hip_bfloat16(val);
            }
        }
    }
}

// ---------------------------------------------------------------------------
// Flash-style causal attention, split-K across 4 waves per Q block
// (unchanged from R4).
// ---------------------------------------------------------------------------
__global__ __launch_bounds__(256, 4) void attn_kernel(
    const __hip_bfloat16* __restrict__ qs,
    const __hip_bfloat16* __restrict__ kb,
    const __hip_bfloat16* __restrict__ vT,
    float* __restrict__ out)
{
    __shared__ unsigned int Ps[4][16 * 36];   // per-wave P buffers (9216 B)
    __shared__ float Os[4][16][64];           // per-wave partial O (16 KB)
    __shared__ float Ll[4][16];               // per-wave partial l
    const int tid  = threadIdx.x;
    const int w    = tid >> 6;                // wave 0..3 = key-stripe
    const int lane = tid & 63;
    const int c    = lane & 15;
    const int quad = lane >> 4;

    const int g  = blockIdx.x;                // 0..1023
    const int b  = g & 3;
    const int jj = g >> 2;                    // 0..255
    const int m_ = jj >> 6, r_ = jj & 63;
    const int t  = (m_ == 0) ? r_ : (m_ == 1) ? (127 - r_)
                 : (m_ == 2) ? (128 + r_) : (255 - r_);
    const int q0 = t << 4;
    const int Td = t >> 2;                    // diagonal 64-key tile index

    const __hip_bfloat16* kbb = kb + (size_t)b * SEQ * HD;
    const __hip_bfloat16* vTb = vT + (size_t)b * HD * SEQ;

    const __hip_bfloat16* qp = qs + ((size_t)b * SEQ + q0 + c) * HD + quad * 8;
    const short8 aq0 = ld8g(qp);
    const short8 aq1 = ld8g(qp + 32);

    f32x4 o0 = {0.f,0.f,0.f,0.f}, o1 = o0, o2 = o0, o3 = o0;
    f32x4 lp = {0.f,0.f,0.f,0.f};
    const f32x4 z = {0.f,0.f,0.f,0.f};

    for (int T = w; T <= Td; T += 4) {
        const int k0 = T << 6;

        const __hip_bfloat16* kp = kbb + (size_t)(k0 + c) * HD + quad * 8;
        f32x4 sf[4];
#pragma unroll
        for (int f = 0; f < 4; ++f) {
            const short8 bk0 = ld8g(kp + f * (16 * HD));
            const short8 bk1 = ld8g(kp + f * (16 * HD) + 32);
            sf[f] = __builtin_amdgcn_mfma_f32_16x16x32_bf16(aq0, bk0, z, 0, 0, 0);
            sf[f] = __builtin_amdgcn_mfma_f32_16x16x32_bf16(aq1, bk1, sf[f], 0, 0, 0);
        }

        if (T == Td) {                        // diagonal tile: causal mask
#pragma unroll
            for (int f = 0; f < 4; ++f) {
                const int key = k0 + f * 16 + c;
#pragma unroll
                for (int r = 0; r < 4; ++r)
                    if (key > q0 + quad * 4 + r) sf[f][r] = -1e30f;
            }
        }

        float p[4][4];
#pragma unroll
        for (int f = 0; f < 4; ++f)
#pragma unroll
            for (int r = 0; r < 4; ++r)
                p[f][r] = __expf(sf[f][r]);
#pragma unroll
        for (int r = 0; r < 4; ++r) {
            lp[r] += (p[0][r] + p[1][r]) + (p[2][r] + p[3][r]);
            uint2 dd;
            dd.x = (unsigned int)bfb(p[0][r]) | ((unsigned int)bfb(p[1][r]) << 16);
            dd.y = (unsigned int)bfb(p[2][r]) | ((unsigned int)bfb(p[3][r]) << 16);
            *(uint2*)&Ps[w][(quad * 4 + r) * 36 + c * 2] = dd;   // pos = c*4 + f
        }

        const short8 ap0 = ld8l(&Ps[w][c * 36 + quad * 4]);
        const short8 ap1 = ld8l(&Ps[w][c * 36 + 16 + quad * 4]);

        const __hip_bfloat16* vp = vTb + (size_t)c * SEQ + k0 + quad * 8;
        {
            const short8 bv0 = ld8g(vp);
            const short8 bv1 = ld8g(vp + 32);
            o0 = __builtin_amdgcn_mfma_f32_16x16x32_bf16(ap0, bv0, o0, 0, 0, 0);
            o0 = __builtin_amdgcn_mfma_f32_16x16x32_bf16(ap1, bv1, o0, 0, 0, 0);
        }
        {
            const short8 bv0 = ld8g(vp + 16 * SEQ);
            const short8 bv1 = ld8g(vp + 16 * SEQ + 32);
            o1 = __builtin_amdgcn_mfma_f32_16x16x32_bf16(ap0, bv0, o1, 0, 0, 0);
            o1 = __builtin_amdgcn_mfma_f32_16x16x32_bf16(ap1, bv1, o1, 0, 0, 0);
        }
        {
            const short8 bv0 = ld8g(vp + 32 * SEQ);
            const short8 bv1 = ld8g(vp + 32 * SEQ + 32);
            o2 = __builtin_amdgcn_mfma_f32_16x16x32_bf16(ap0, bv0, o2, 0, 0, 0);
            o2 = __builtin_amdgcn_mfma_f32_16x16x32_bf16(ap1, bv1, o2, 0, 0, 0);
        }
        {
            const short8 bv0 = ld8g(vp + 48 * SEQ);
            const short8 bv1 = ld8g(vp + 48 * SEQ + 32);
            o3 = __builtin_amdgcn_mfma_f32_16x16x32_bf16(ap0, bv0, o3, 0, 0, 0);
            o3 = __builtin_amdgcn_mfma_f32_16x16x32_bf16(ap1, bv1, o3, 0, 0, 0);
        }
    }

    // per-wave l reduction across the 16 cols
#pragma unroll
    for (int r = 0; r < 4; ++r) {
        float v = lp[r];
        v += __shfl_xor(v, 1, 64);
        v += __shfl_xor(v, 2, 64);
        v += __shfl_xor(v, 4, 64);
        v += __shfl_xor(v, 8, 64);
        lp[r] = v;
    }

    // stage partials: Os[w][row][col], Ll[w][row]
#pragma unroll
    for (int r = 0; r < 4; ++r) {
        const int row = quad * 4 + r;
        Os[w][row][ 0 + c] = o0[r];
        Os[w][row][16 + c] = o1[r];
        Os[w][row][32 + c] = o2[r];
        Os[w][row][48 + c] = o3[r];
        if (c == 0) Ll[w][row] = lp[r];
    }
    __syncthreads();

    // combine: 256 threads x 4 elements, out = (sum o) / (sum l)
    float* ob = out + ((size_t)b * SEQ + q0) * HD;
#pragma unroll
    for (int i = 0; i < 4; ++i) {
        const int idx = tid + 256 * i;        // 0..1023
        const int row = idx >> 6;
        const int col = idx & 63;
        const float num = (Os[0][row][col] + Os[1][row][col])
                        + (Os[2][row][col] + Os[3][row][col]);
        const float den = (Ll[0][row] + Ll[1][row])
                        + (Ll[2][row] + Ll[3][row]);
        ob[row * HD + col] = num / den;
    }
}

// ---------------------------------------------------------------------------
extern "C" void kernel_launch(void* const* d_in, const int* in_sizes, int n_in,
                              void* d_out, int out_size, void* d_ws, size_t ws_size,
                              hipStream_t stream)
{
    (void)in_sizes; (void)n_in; (void)out_size; (void)ws_size;
    const float* x  = (const float*)d_in[0];
    const float* Wk = (const float*)d_in[1];
    const float* Wq = (const float*)d_in[2];
    const float* Wv = (const float*)d_in[3];
    float* out = (float*)d_out;

    const size_t BSH = (size_t)BATCH * SEQ * HD;        // 1,048,576 elems
    __hip_bfloat16* qs = (__hip_bfloat16*)d_ws;         // 2 MB
    __hip_bfloat16* kb = qs + BSH;                      // 2 MB
    __hip_bfloat16* vT = kb + BSH;                      // 2 MB
    __hip_bfloat16* WT = vT + BSH;                      // 384 KB (6.4 MB ws)

    prep_w<<<192, 256, 0, stream>>>(Wk, Wq, Wv, WT);
    gemm_proj<<<BATCH * SEQ / 32, 256, 0, stream>>>(x, WT, qs, kb, vT);
    attn_kernel<<<BATCH * (SEQ / 16), 256, 0, stream>>>(qs, kb, vT, out);
}

// Round 6
// 208.372 us; speedup vs baseline: 1.0169x; 1.0169x over previous
//
#include <hip/hip_runtime.h>
#include <hip/hip_bf16.h>
#include <math.h>

#define BATCH 4
#define SEQ   4096
#define EMB   1024
#define HD    64
#define SCALE 0.03125f   // EMB^-0.5 = 1/32, exact in bf16

typedef __attribute__((ext_vector_type(8))) short short8;  // 8 bf16 = 4 VGPRs
typedef __attribute__((ext_vector_type(4))) float f32x4;

__device__ __forceinline__ short8 ld8g(const __hip_bfloat16* p) {
    union { uint4 u; short8 s; } cv;
    cv.u = *(const uint4*)p;          // 16B aligned by construction
    return cv.s;
}
__device__ __forceinline__ short8 ld8l(const unsigned int* p) {
    union { uint4 u; short8 s; } cv;
    cv.u = *(const uint4*)p;
    return cv.s;
}
__device__ __forceinline__ unsigned short bfb(float a) {
    union { __hip_bfloat16 h; unsigned short u; } cv;
    cv.h = __hip_bfloat16(a);
    return cv.u;
}

// ---------------------------------------------------------------------------
// prep_w: W{q,k,v} fp32 [1024][64] -> WT bf16 [192][1024]  (unchanged)
// ---------------------------------------------------------------------------
__global__ __launch_bounds__(256) void prep_w(
    const float* __restrict__ Wk, const float* __restrict__ Wq,
    const float* __restrict__ Wv, __hip_bfloat16* __restrict__ WT)
{
    const int n = blockIdx.x;                 // 0..191
    const float* W = (n < 64) ? Wq : (n < 128) ? Wk : Wv;
    const int h = n & 63;
    const int t = threadIdx.x;
#pragma unroll
    for (int i = 0; i < 4; ++i) {
        const int k = i * 256 + t;
        WT[(size_t)n * EMB + k] = __hip_bfloat16(W[(size_t)k * HD + h]);
    }
}

// ---------------------------------------------------------------------------
// gemm_proj v3: [16384 x 1024] x [1024 x 192] via 16x16x32 bf16 MFMA.
// R5 post-mortem: the scheduler picked a minimal-liveness schedule (VGPR=48,
// load->wait->MFMA serialized). v3 forces overlap in source:
//   - explicit depth-2 register prefetch (bf[2][6], xa/xb[2]): step s+1's
//     8 loads issue before step s's MFMAs, values live across the MFMA block
//   - K-split 2, block = 8 waves (2 rw x 2 nh x 2 kh) = 512 thr; 4096 waves
//     = 4 waves/SIMD for TLP; partials combine through padded LDS
// __launch_bounds__(512,4) caps VGPR at 128 (expected use ~110, no spill).
// ---------------------------------------------------------------------------
__global__ __launch_bounds__(512, 4) void gemm_proj(
    const float* __restrict__ x,
    const __hip_bfloat16* __restrict__ WT,
    __hip_bfloat16* __restrict__ qs,
    __hip_bfloat16* __restrict__ kb,
    __hip_bfloat16* __restrict__ vT)
{
    __shared__ float Pl[32][194];             // stride 194: quad rows 8 banks apart
    const int tid  = threadIdx.x;
    const int lane = tid & 63;
    const int c    = lane & 15;
    const int quad = lane >> 4;
    const int w    = tid >> 6;                // 0..7
    const int rw   = w & 1;                   // row sub-tile (16 rows)
    const int nh   = (w >> 1) & 1;            // col half (96 cols)
    const int kh   = w >> 2;                  // K half (512)
    const int R0   = blockIdx.x * 32;
    const int arow = R0 + rw * 16 + c;        // A-operand row for this lane

    f32x4 acc[6];
#pragma unroll
    for (int f = 0; f < 6; ++f) acc[f] = (f32x4){0.f, 0.f, 0.f, 0.f};

    const float* xp = x + (size_t)arow * EMB + kh * 512 + quad * 8;
    const __hip_bfloat16* wp = WT + (size_t)(nh * 96 + c) * EMB + kh * 512 + quad * 8;

    // ---- depth-2 software pipeline over 16 K-steps of 32 ----
    float4 xa[2], xb[2];
    short8 bf[2][6];
    xa[0] = *(const float4*)(xp);
    xb[0] = *(const float4*)(xp + 4);
#pragma unroll
    for (int f = 0; f < 6; ++f) bf[0][f] = ld8g(wp + (size_t)f * 16 * EMB);

#pragma unroll
    for (int s = 0; s < 16; ++s) {
        const int cur = s & 1, nxt = cur ^ 1;
        if (s < 15) {                          // issue next step's loads first
            xa[nxt] = *(const float4*)(xp + (s + 1) * 32);
            xb[nxt] = *(const float4*)(xp + (s + 1) * 32 + 4);
#pragma unroll
            for (int f = 0; f < 6; ++f)
                bf[nxt][f] = ld8g(wp + (size_t)f * 16 * EMB + (s + 1) * 32);
        }
        union { unsigned short u[8]; short8 s8; } av;
        av.u[0] = bfb(xa[cur].x); av.u[1] = bfb(xa[cur].y);
        av.u[2] = bfb(xa[cur].z); av.u[3] = bfb(xa[cur].w);
        av.u[4] = bfb(xb[cur].x); av.u[5] = bfb(xb[cur].y);
        av.u[6] = bfb(xb[cur].z); av.u[7] = bfb(xb[cur].w);
#pragma unroll
        for (int f = 0; f < 6; ++f)
            acc[f] = __builtin_amdgcn_mfma_f32_16x16x32_bf16(av.s8, bf[cur][f], acc[f], 0, 0, 0);
    }

    // ---- combine K-halves through LDS ----
    if (kh == 1) {
#pragma unroll
        for (int f = 0; f < 6; ++f)
#pragma unroll
            for (int r = 0; r < 4; ++r)
                Pl[rw * 16 + quad * 4 + r][nh * 96 + f * 16 + c] = acc[f][r];
    }
    __syncthreads();
    if (kh == 0) {
#pragma unroll
        for (int f = 0; f < 6; ++f)
#pragma unroll
            for (int r = 0; r < 4; ++r)
                acc[f][r] += Pl[rw * 16 + quad * 4 + r][nh * 96 + f * 16 + c];

        // ---- epilogue: D[m = quad*4+r][n = nh*96 + f*16 + c] ----
#pragma unroll
        for (int f = 0; f < 6; ++f) {
#pragma unroll
            for (int r = 0; r < 4; ++r) {
                const int m = R0 + rw * 16 + quad * 4 + r;   // global row
                const int n = nh * 96 + f * 16 + c;          // 0..191
                const float val = acc[f][r];
                if (n < 64) {
                    qs[(size_t)m * HD + n] = __hip_bfloat16(val * SCALE);
                } else if (n < 128) {
                    kb[(size_t)m * HD + (n - 64)] = __hip_bfloat16(val);
                } else {
                    const int b  = m >> 12;
                    const int sq = m & (SEQ - 1);
                    const int sp = (sq & ~63) | ((sq & 15) << 2) | ((sq >> 4) & 3);
                    vT[((size_t)b * HD + (n - 128)) * SEQ + sp] = __hip_bfloat16(val);
                }
            }
        }
    }
}

// ---------------------------------------------------------------------------
// Flash-style causal attention, split-K across 4 waves per Q block
// (unchanged from R4).
// ---------------------------------------------------------------------------
__global__ __launch_bounds__(256, 4) void attn_kernel(
    const __hip_bfloat16* __restrict__ qs,
    const __hip_bfloat16* __restrict__ kb,
    const __hip_bfloat16* __restrict__ vT,
    float* __restrict__ out)
{
    __shared__ unsigned int Ps[4][16 * 36];   // per-wave P buffers (9216 B)
    __shared__ float Os[4][16][64];           // per-wave partial O (16 KB)
    __shared__ float Ll[4][16];               // per-wave partial l
    const int tid  = threadIdx.x;
    const int w    = tid >> 6;                // wave 0..3 = key-stripe
    const int lane = tid & 63;
    const int c    = lane & 15;
    const int quad = lane >> 4;

    const int g  = blockIdx.x;                // 0..1023
    const int b  = g & 3;
    const int jj = g >> 2;                    // 0..255
    const int m_ = jj >> 6, r_ = jj & 63;
    const int t  = (m_ == 0) ? r_ : (m_ == 1) ? (127 - r_)
                 : (m_ == 2) ? (128 + r_) : (255 - r_);
    const int q0 = t << 4;
    const int Td = t >> 2;                    // diagonal 64-key tile index

    const __hip_bfloat16* kbb = kb + (size_t)b * SEQ * HD;
    const __hip_bfloat16* vTb = vT + (size_t)b * HD * SEQ;

    const __hip_bfloat16* qp = qs + ((size_t)b * SEQ + q0 + c) * HD + quad * 8;
    const short8 aq0 = ld8g(qp);
    const short8 aq1 = ld8g(qp + 32);

    f32x4 o0 = {0.f,0.f,0.f,0.f}, o1 = o0, o2 = o0, o3 = o0;
    f32x4 lp = {0.f,0.f,0.f,0.f};
    const f32x4 z = {0.f,0.f,0.f,0.f};

    for (int T = w; T <= Td; T += 4) {
        const int k0 = T << 6;

        const __hip_bfloat16* kp = kbb + (size_t)(k0 + c) * HD + quad * 8;
        f32x4 sf[4];
#pragma unroll
        for (int f = 0; f < 4; ++f) {
            const short8 bk0 = ld8g(kp + f * (16 * HD));
            const short8 bk1 = ld8g(kp + f * (16 * HD) + 32);
            sf[f] = __builtin_amdgcn_mfma_f32_16x16x32_bf16(aq0, bk0, z, 0, 0, 0);
            sf[f] = __builtin_amdgcn_mfma_f32_16x16x32_bf16(aq1, bk1, sf[f], 0, 0, 0);
        }

        if (T == Td) {                        // diagonal tile: causal mask
#pragma unroll
            for (int f = 0; f < 4; ++f) {
                const int key = k0 + f * 16 + c;
#pragma unroll
                for (int r = 0; r < 4; ++r)
                    if (key > q0 + quad * 4 + r) sf[f][r] = -1e30f;
            }
        }

        float p[4][4];
#pragma unroll
        for (int f = 0; f < 4; ++f)
#pragma unroll
            for (int r = 0; r < 4; ++r)
                p[f][r] = __expf(sf[f][r]);
#pragma unroll
        for (int r = 0; r < 4; ++r) {
            lp[r] += (p[0][r] + p[1][r]) + (p[2][r] + p[3][r]);
            uint2 dd;
            dd.x = (unsigned int)bfb(p[0][r]) | ((unsigned int)bfb(p[1][r]) << 16);
            dd.y = (unsigned int)bfb(p[2][r]) | ((unsigned int)bfb(p[3][r]) << 16);
            *(uint2*)&Ps[w][(quad * 4 + r) * 36 + c * 2] = dd;   // pos = c*4 + f
        }

        const short8 ap0 = ld8l(&Ps[w][c * 36 + quad * 4]);
        const short8 ap1 = ld8l(&Ps[w][c * 36 + 16 + quad * 4]);

        const __hip_bfloat16* vp = vTb + (size_t)c * SEQ + k0 + quad * 8;
        {
            const short8 bv0 = ld8g(vp);
            const short8 bv1 = ld8g(vp + 32);
            o0 = __builtin_amdgcn_mfma_f32_16x16x32_bf16(ap0, bv0, o0, 0, 0, 0);
            o0 = __builtin_amdgcn_mfma_f32_16x16x32_bf16(ap1, bv1, o0, 0, 0, 0);
        }
        {
            const short8 bv0 = ld8g(vp + 16 * SEQ);
            const short8 bv1 = ld8g(vp + 16 * SEQ + 32);
            o1 = __builtin_amdgcn_mfma_f32_16x16x32_bf16(ap0, bv0, o1, 0, 0, 0);
            o1 = __builtin_amdgcn_mfma_f32_16x16x32_bf16(ap1, bv1, o1, 0, 0, 0);
        }
        {
            const short8 bv0 = ld8g(vp + 32 * SEQ);
            const short8 bv1 = ld8g(vp + 32 * SEQ + 32);
            o2 = __builtin_amdgcn_mfma_f32_16x16x32_bf16(ap0, bv0, o2, 0, 0, 0);
            o2 = __builtin_amdgcn_mfma_f32_16x16x32_bf16(ap1, bv1, o2, 0, 0, 0);
        }
        {
            const short8 bv0 = ld8g(vp + 48 * SEQ);
            const short8 bv1 = ld8g(vp + 48 * SEQ + 32);
            o3 = __builtin_amdgcn_mfma_f32_16x16x32_bf16(ap0, bv0, o3, 0, 0, 0);
            o3 = __builtin_amdgcn_mfma_f32_16x16x32_bf16(ap1, bv1, o3, 0, 0, 0);
        }
    }

    // per-wave l reduction across the 16 cols
#pragma unroll
    for (int r = 0; r < 4; ++r) {
        float v = lp[r];
        v += __shfl_xor(v, 1, 64);
        v += __shfl_xor(v, 2, 64);
        v += __shfl_xor(v, 4, 64);
        v += __shfl_xor(v, 8, 64);
        lp[r] = v;
    }

    // stage partials: Os[w][row][col], Ll[w][row]
#pragma unroll
    for (int r = 0; r < 4; ++r) {
        const int row = quad * 4 + r;
        Os[w][row][ 0 + c] = o0[r];
        Os[w][row][16 + c] = o1[r];
        Os[w][row][32 + c] = o2[r];
        Os[w][row][48 + c] = o3[r];
        if (c == 0) Ll[w][row] = lp[r];
    }
    __syncthreads();

    // combine: 256 threads x 4 elements, out = (sum o) / (sum l)
    float* ob = out + ((size_t)b * SEQ + q0) * HD;
#pragma unroll
    for (int i = 0; i < 4; ++i) {
        const int idx = tid + 256 * i;        // 0..1023
        const int row = idx >> 6;
        const int col = idx & 63;
        const float num = (Os[0][row][col] + Os[1][row][col])
                        + (Os[2][row][col] + Os[3][row][col]);
        const float den = (Ll[0][row] + Ll[1][row])
                        + (Ll[2][row] + Ll[3][row]);
        ob[row * HD + col] = num / den;
    }
}

// ---------------------------------------------------------------------------
extern "C" void kernel_launch(void* const* d_in, const int* in_sizes, int n_in,
                              void* d_out, int out_size, void* d_ws, size_t ws_size,
                              hipStream_t stream)
{
    (void)in_sizes; (void)n_in; (void)out_size; (void)ws_size;
    const float* x  = (const float*)d_in[0];
    const float* Wk = (const float*)d_in[1];
    const float* Wq = (const float*)d_in[2];
    const float* Wv = (const float*)d_in[3];
    float* out = (float*)d_out;

    const size_t BSH = (size_t)BATCH * SEQ * HD;        // 1,048,576 elems
    __hip_bfloat16* qs = (__hip_bfloat16*)d_ws;         // 2 MB
    __hip_bfloat16* kb = qs + BSH;                      // 2 MB
    __hip_bfloat16* vT = kb + BSH;                      // 2 MB
    __hip_bfloat16* WT = vT + BSH;                      // 384 KB (6.4 MB ws)

    prep_w<<<192, 256, 0, stream>>>(Wk, Wq, Wv, WT);
    gemm_proj<<<BATCH * SEQ / 32, 512, 0, stream>>>(x, WT, qs, kb, vT);
    attn_kernel<<<BATCH * (SEQ / 16), 256, 0, stream>>>(qs, kb, vT, out);
}

// Round 7
// 185.616 us; speedup vs baseline: 1.1416x; 1.1226x over previous
//
#include <hip/hip_runtime.h>
#include <hip/hip_bf16.h>
#include <math.h>

#define BATCH 4
#define SEQ   4096
#define EMB   1024
#define HD    64
#define SCALE 0.03125f   // EMB^-0.5 = 1/32, exact in bf16

typedef __attribute__((ext_vector_type(8))) short short8;  // 8 bf16 = 4 VGPRs
typedef __attribute__((ext_vector_type(4))) float f32x4;

__device__ __forceinline__ short8 ld8g(const __hip_bfloat16* p) {
    union { uint4 u; short8 s; } cv;
    cv.u = *(const uint4*)p;          // 16B aligned by construction
    return cv.s;
}
__device__ __forceinline__ short8 ld8l(const void* p) {
    union { uint4 u; short8 s; } cv;
    cv.u = *(const uint4*)p;
    return cv.s;
}
__device__ __forceinline__ unsigned short bfb(float a) {
    union { __hip_bfloat16 h; unsigned short u; } cv;
    cv.h = __hip_bfloat16(a);
    return cv.u;
}

// async global->LDS DMA, 16 B/lane. LDS dest = wave-uniform base + lane*16.
__device__ __forceinline__ void gld16(const void* g, const void* lds_base) {
    __builtin_amdgcn_global_load_lds(
        (const __attribute__((address_space(1))) void*)(unsigned long long)(uintptr_t)g,
        (__attribute__((address_space(3))) void*)(unsigned)(uintptr_t)lds_base,
        16, 0, 0);
}

// ---------------------------------------------------------------------------
// prep_w: W{q,k,v} fp32 [1024][64] -> WT bf16 [192][1024]  (unchanged)
// ---------------------------------------------------------------------------
__global__ __launch_bounds__(256) void prep_w(
    const float* __restrict__ Wk, const float* __restrict__ Wq,
    const float* __restrict__ Wv, __hip_bfloat16* __restrict__ WT)
{
    const int n = blockIdx.x;                 // 0..191
    const float* W = (n < 64) ? Wq : (n < 128) ? Wk : Wv;
    const int h = n & 63;
    const int t = threadIdx.x;
#pragma unroll
    for (int i = 0; i < 4; ++i) {
        const int k = i * 256 + t;
        WT[(size_t)n * EMB + k] = __hip_bfloat16(W[(size_t)k * HD + h]);
    }
}

// ---------------------------------------------------------------------------
// gemm_proj v4 (m97-style): [16384 x 1024] x [1024 x 192], 16x16x32 bf16 MFMA.
// R5/R6 post-mortem: compiler register-serializes direct global loads (VGPR
// stuck at 44-48). v4 stages A (x fp32) and B (WT bf16) via async
// global_load_lds DMA: latency lives in vmcnt, not registers.
//   block = 256 thr (4 waves) = 32 rows x 192 cols; BK=64, 16 stage/compute
//   steps, single-buffered 2-barrier loop.
// DMA LDS side is fixed base+lane*16 (no padding possible), so bank
// de-conflict is done with a GLOBAL-side XOR swizzle:
//   A: [8 groups of 4 rows][1040 B]; row r: 16-B chunk stored at position
//      ps holds global chunk ci = ps ^ ((r&3)<<1)   (even XOR keeps 32-B
//      fragment reads contiguous); group pad 16 B -> 2-way reads (free).
//   B: [24 groups of 8 rows][1040 B]; ps holds ci = ps ^ (r&7).
// ---------------------------------------------------------------------------
__global__ __launch_bounds__(256) void gemm_proj(
    const float* __restrict__ x,
    const __hip_bfloat16* __restrict__ WT,
    __hip_bfloat16* __restrict__ qs,
    __hip_bfloat16* __restrict__ kb,
    __hip_bfloat16* __restrict__ vT)
{
    __shared__ __align__(16) char sm[8 * 1040 + 24 * 1040];   // 33,280 B
    char* smA = sm;                    // A: 8 groups x 1040
    char* smB = sm + 8 * 1040;        // B: 24 groups x 1040

    const int tid  = threadIdx.x;
    const int lane = tid & 63;
    const int c    = lane & 15;
    const int quad = lane >> 4;
    const int w    = tid >> 6;        // 0..3
    const int rw   = w & 1;           // row half (16 rows)
    const int nh   = w >> 1;          // col half (96 cols)
    const int R0   = blockIdx.x * 32;

    // DMA lane decompositions (fixed per lane)
    const int rrA = lane >> 4;        // A: row-in-group 0..3
    const int ciA = (lane & 15) ^ (rrA << 1);   // global chunk for stored pos
    const int rrB = lane >> 3;        // B: row-in-group 0..7
    const int ciB = (lane & 7) ^ rrB;

    // compute-side invariants
    const int rA   = rw * 16 + c;     // A row this lane consumes
    const int gA   = rA >> 2;
    const int rrr  = rA & 3;
    const char* paBase = smA + gA * 1040 + rrr * 256;

    f32x4 acc[6];
#pragma unroll
    for (int f = 0; f < 6; ++f) acc[f] = (f32x4){0.f, 0.f, 0.f, 0.f};

    for (int s = 0; s < 16; ++s) {
        const int k0 = s * 64;

        // ---- stage: A 2 groups + B 6 groups per wave (async DMA) ----
#pragma unroll
        for (int j = 0; j < 2; ++j) {
            const int g = w * 2 + j;
            const float* ga = x + (size_t)(R0 + g * 4 + rrA) * EMB + k0 + ciA * 4;
            gld16(ga, smA + g * 1040);
        }
#pragma unroll
        for (int j = 0; j < 6; ++j) {
            const int gb = w * 6 + j;
            const __hip_bfloat16* gw = WT + (size_t)(gb * 8 + rrB) * EMB + k0 + ciB * 8;
            gld16(gw, smB + gb * 1040);
        }
        __syncthreads();              // drains vmcnt (DMA) + barrier

        // ---- compute: 2 K-steps of 32 ----
#pragma unroll
        for (int ks = 0; ks < 2; ++ks) {
            const int ci0 = ks * 8 + quad * 2;          // even
            const int ps0 = ci0 ^ (rrr << 1);
            const char* pa = paBase + ps0 * 16;
            const float4 fa = *(const float4*)pa;
            const float4 fb = *(const float4*)(pa + 16);
            union { unsigned short u[8]; short8 s8; } av;
            av.u[0] = bfb(fa.x); av.u[1] = bfb(fa.y);
            av.u[2] = bfb(fa.z); av.u[3] = bfb(fa.w);
            av.u[4] = bfb(fb.x); av.u[5] = bfb(fb.y);
            av.u[6] = bfb(fb.z); av.u[7] = bfb(fb.w);
#pragma unroll
            for (int f = 0; f < 6; ++f) {
                const int n   = nh * 96 + f * 16 + c;
                const int gB  = n >> 3;
                const int rB  = n & 7;
                const int psb = (ks * 4 + quad) ^ rB;
                const short8 bfrag = ld8l(smB + gB * 1040 + rB * 128 + psb * 16);
                acc[f] = __builtin_amdgcn_mfma_f32_16x16x32_bf16(av.s8, bfrag, acc[f], 0, 0, 0);
            }
        }
        __syncthreads();              // all reads done before next overwrite
    }

    // ---- epilogue: D[m = rw*16 + quad*4 + r][n = nh*96 + f*16 + c] ----
#pragma unroll
    for (int f = 0; f < 6; ++f) {
#pragma unroll
        for (int r = 0; r < 4; ++r) {
            const int m = R0 + rw * 16 + quad * 4 + r;   // global row
            const int n = nh * 96 + f * 16 + c;          // 0..191
            const float val = acc[f][r];
            if (n < 64) {
                qs[(size_t)m * HD + n] = __hip_bfloat16(val * SCALE);
            } else if (n < 128) {
                kb[(size_t)m * HD + (n - 64)] = __hip_bfloat16(val);
            } else {
                const int b  = m >> 12;
                const int sq = m & (SEQ - 1);
                const int sp = (sq & ~63) | ((sq & 15) << 2) | ((sq >> 4) & 3);
                vT[((size_t)b * HD + (n - 128)) * SEQ + sp] = __hip_bfloat16(val);
            }
        }
    }
}

// ---------------------------------------------------------------------------
// Flash-style causal attention, split-K across 8 waves per Q block.
// R6 post-mortem: per-tile loads register-serialize (~5K cyc/tile); grid gave
// only ~2 waves/SIMD resident. 8 stripes x 1024 blocks = 8192 waves = 8/SIMD
// (LDS 51.7 KB -> 3 blocks/CU) so cross-wave TLP hides the serialized chain.
// ---------------------------------------------------------------------------
__global__ __launch_bounds__(512) void attn_kernel(
    const __hip_bfloat16* __restrict__ qs,
    const __hip_bfloat16* __restrict__ kb,
    const __hip_bfloat16* __restrict__ vT,
    float* __restrict__ out)
{
    __shared__ unsigned int Ps[8][16 * 36];   // per-wave P buffers (18,432 B)
    __shared__ float Os[8][16][64];           // per-wave partial O (32,768 B)
    __shared__ float Ll[8][16];               // per-wave partial l
    const int tid  = threadIdx.x;
    const int w    = tid >> 6;                // wave 0..7 = key-stripe
    const int lane = tid & 63;
    const int c    = lane & 15;
    const int quad = lane >> 4;

    const int g  = blockIdx.x;                // 0..1023
    const int b  = g & 3;
    const int jj = g >> 2;                    // 0..255
    const int m_ = jj >> 6, r_ = jj & 63;
    const int t  = (m_ == 0) ? r_ : (m_ == 1) ? (127 - r_)
                 : (m_ == 2) ? (128 + r_) : (255 - r_);
    const int q0 = t << 4;
    const int Td = t >> 2;                    // diagonal 64-key tile index

    const __hip_bfloat16* kbb = kb + (size_t)b * SEQ * HD;
    const __hip_bfloat16* vTb = vT + (size_t)b * HD * SEQ;

    const __hip_bfloat16* qp = qs + ((size_t)b * SEQ + q0 + c) * HD + quad * 8;
    const short8 aq0 = ld8g(qp);
    const short8 aq1 = ld8g(qp + 32);

    f32x4 o0 = {0.f,0.f,0.f,0.f}, o1 = o0, o2 = o0, o3 = o0;
    f32x4 lp = {0.f,0.f,0.f,0.f};
    const f32x4 z = {0.f,0.f,0.f,0.f};

    for (int T = w; T <= Td; T += 8) {
        const int k0 = T << 6;

        const __hip_bfloat16* kp = kbb + (size_t)(k0 + c) * HD + quad * 8;
        f32x4 sf[4];
#pragma unroll
        for (int f = 0; f < 4; ++f) {
            const short8 bk0 = ld8g(kp + f * (16 * HD));
            const short8 bk1 = ld8g(kp + f * (16 * HD) + 32);
            sf[f] = __builtin_amdgcn_mfma_f32_16x16x32_bf16(aq0, bk0, z, 0, 0, 0);
            sf[f] = __builtin_amdgcn_mfma_f32_16x16x32_bf16(aq1, bk1, sf[f], 0, 0, 0);
        }

        if (T == Td) {                        // diagonal tile: causal mask
#pragma unroll
            for (int f = 0; f < 4; ++f) {
                const int key = k0 + f * 16 + c;
#pragma unroll
                for (int r = 0; r < 4; ++r)
                    if (key > q0 + quad * 4 + r) sf[f][r] = -1e30f;
            }
        }

        float p[4][4];
#pragma unroll
        for (int f = 0; f < 4; ++f)
#pragma unroll
            for (int r = 0; r < 4; ++r)
                p[f][r] = __expf(sf[f][r]);
#pragma unroll
        for (int r = 0; r < 4; ++r) {
            lp[r] += (p[0][r] + p[1][r]) + (p[2][r] + p[3][r]);
            uint2 dd;
            dd.x = (unsigned int)bfb(p[0][r]) | ((unsigned int)bfb(p[1][r]) << 16);
            dd.y = (unsigned int)bfb(p[2][r]) | ((unsigned int)bfb(p[3][r]) << 16);
            *(uint2*)&Ps[w][(quad * 4 + r) * 36 + c * 2] = dd;   // pos = c*4 + f
        }

        const short8 ap0 = ld8l(&Ps[w][c * 36 + quad * 4]);
        const short8 ap1 = ld8l(&Ps[w][c * 36 + 16 + quad * 4]);

        const __hip_bfloat16* vp = vTb + (size_t)c * SEQ + k0 + quad * 8;
        {
            const short8 bv0 = ld8g(vp);
            const short8 bv1 = ld8g(vp + 32);
            o0 = __builtin_amdgcn_mfma_f32_16x16x32_bf16(ap0, bv0, o0, 0, 0, 0);
            o0 = __builtin_amdgcn_mfma_f32_16x16x32_bf16(ap1, bv1, o0, 0, 0, 0);
        }
        {
            const short8 bv0 = ld8g(vp + 16 * SEQ);
            const short8 bv1 = ld8g(vp + 16 * SEQ + 32);
            o1 = __builtin_amdgcn_mfma_f32_16x16x32_bf16(ap0, bv0, o1, 0, 0, 0);
            o1 = __builtin_amdgcn_mfma_f32_16x16x32_bf16(ap1, bv1, o1, 0, 0, 0);
        }
        {
            const short8 bv0 = ld8g(vp + 32 * SEQ);
            const short8 bv1 = ld8g(vp + 32 * SEQ + 32);
            o2 = __builtin_amdgcn_mfma_f32_16x16x32_bf16(ap0, bv0, o2, 0, 0, 0);
            o2 = __builtin_amdgcn_mfma_f32_16x16x32_bf16(ap1, bv1, o2, 0, 0, 0);
        }
        {
            const short8 bv0 = ld8g(vp + 48 * SEQ);
            const short8 bv1 = ld8g(vp + 48 * SEQ + 32);
            o3 = __builtin_amdgcn_mfma_f32_16x16x32_bf16(ap0, bv0, o3, 0, 0, 0);
            o3 = __builtin_amdgcn_mfma_f32_16x16x32_bf16(ap1, bv1, o3, 0, 0, 0);
        }
    }

    // per-wave l reduction across the 16 cols
#pragma unroll
    for (int r = 0; r < 4; ++r) {
        float v = lp[r];
        v += __shfl_xor(v, 1, 64);
        v += __shfl_xor(v, 2, 64);
        v += __shfl_xor(v, 4, 64);
        v += __shfl_xor(v, 8, 64);
        lp[r] = v;
    }

    // stage partials: Os[w][row][col], Ll[w][row]
#pragma unroll
    for (int r = 0; r < 4; ++r) {
        const int row = quad * 4 + r;
        Os[w][row][ 0 + c] = o0[r];
        Os[w][row][16 + c] = o1[r];
        Os[w][row][32 + c] = o2[r];
        Os[w][row][48 + c] = o3[r];
        if (c == 0) Ll[w][row] = lp[r];
    }
    __syncthreads();

    // combine: 512 threads x 2 elements, out = (sum o) / (sum l)
    float* ob = out + ((size_t)b * SEQ + q0) * HD;
#pragma unroll
    for (int i = 0; i < 2; ++i) {
        const int idx = tid + 512 * i;        // 0..1023
        const int row = idx >> 6;
        const int col = idx & 63;
        float num = 0.f, den = 0.f;
#pragma unroll
        for (int s = 0; s < 8; ++s) {
            num += Os[s][row][col];
            den += Ll[s][row];
        }
        ob[row * HD + col] = num / den;
    }
}

// ---------------------------------------------------------------------------
extern "C" void kernel_launch(void* const* d_in, const int* in_sizes, int n_in,
                              void* d_out, int out_size, void* d_ws, size_t ws_size,
                              hipStream_t stream)
{
    (void)in_sizes; (void)n_in; (void)out_size; (void)ws_size;
    const float* x  = (const float*)d_in[0];
    const float* Wk = (const float*)d_in[1];
    const float* Wq = (const float*)d_in[2];
    const float* Wv = (const float*)d_in[3];
    float* out = (float*)d_out;

    const size_t BSH = (size_t)BATCH * SEQ * HD;        // 1,048,576 elems
    __hip_bfloat16* qs = (__hip_bfloat16*)d_ws;         // 2 MB
    __hip_bfloat16* kb = qs + BSH;                      // 2 MB
    __hip_bfloat16* vT = kb + BSH;                      // 2 MB
    __hip_bfloat16* WT = vT + BSH;                      // 384 KB (6.4 MB ws)

    prep_w<<<192, 256, 0, stream>>>(Wk, Wq, Wv, WT);
    gemm_proj<<<BATCH * SEQ / 32, 256, 0, stream>>>(x, WT, qs, kb, vT);
    attn_kernel<<<BATCH * (SEQ / 16), 512, 0, stream>>>(qs, kb, vT, out);
}

// Round 8
// 148.242 us; speedup vs baseline: 1.4294x; 1.2521x over previous
//
#include <hip/hip_runtime.h>
#include <hip/hip_bf16.h>
#include <math.h>

#define BATCH 4
#define SEQ   4096
#define EMB   1024
#define HD    64
#define SCALE 0.03125f   // EMB^-0.5 = 1/32, exact in bf16
#define NSTRIPE 4

typedef __attribute__((ext_vector_type(8))) short short8;  // 8 bf16 = 4 VGPRs
typedef __attribute__((ext_vector_type(4))) float f32x4;

__device__ __forceinline__ short8 ld8g(const __hip_bfloat16* p) {
    union { uint4 u; short8 s; } cv;
    cv.u = *(const uint4*)p;
    return cv.s;
}
__device__ __forceinline__ short8 ld8l(const void* p) {
    union { uint4 u; short8 s; } cv;
    cv.u = *(const uint4*)p;
    return cv.s;
}
__device__ __forceinline__ unsigned short bfb(float a) {
    union { __hip_bfloat16 h; unsigned short u; } cv;
    cv.h = __hip_bfloat16(a);
    return cv.u;
}

// async global->LDS DMA, 16 B/lane. LDS dest = wave-uniform base + lane*16.
__device__ __forceinline__ void gld16(const void* g, const void* lds_base) {
    __builtin_amdgcn_global_load_lds(
        (const __attribute__((address_space(1))) void*)(unsigned long long)(uintptr_t)g,
        (__attribute__((address_space(3))) void*)(unsigned)(uintptr_t)lds_base,
        16, 0, 0);
}

// ---------------------------------------------------------------------------
// prep_w v2: coalesced transpose via LDS. R3-R7 version cost ~73 us (hidden
// in the ledger): 786K stride-256B scalar loads. v2: float4 coalesced reads
// -> padded LDS [64][65] -> packed 16-B bf16 column writes.
// Grid 48: blockIdx = wsel*16 + kblk; WT rows 0-63=Wq, 64-127=Wk, 128-191=Wv.
// ---------------------------------------------------------------------------
__global__ __launch_bounds__(256) void prep_w(
    const float* __restrict__ Wk, const float* __restrict__ Wq,
    const float* __restrict__ Wv, __hip_bfloat16* __restrict__ WT)
{
    __shared__ float ls[64][65];
    const int wsel = blockIdx.x >> 4;
    const int kblk = blockIdx.x & 15;
    const int k0   = kblk * 64;
    const float* W = (wsel == 0) ? Wq : (wsel == 1) ? Wk : Wv;
    const int t = threadIdx.x;
#pragma unroll
    for (int i = 0; i < 4; ++i) {
        const int idx = t + i * 256;        // 0..1023
        const int row = idx >> 4;           // k row 0..63
        const int c4  = idx & 15;           // float4 within row
        const float4 v = *(const float4*)(W + (size_t)(k0 + row) * HD + c4 * 4);
        ls[row][c4 * 4 + 0] = v.x; ls[row][c4 * 4 + 1] = v.y;
        ls[row][c4 * 4 + 2] = v.z; ls[row][c4 * 4 + 3] = v.w;
    }
    __syncthreads();
    const int h   = t >> 2;
    const int kk0 = (t & 3) * 16;
#pragma unroll
    for (int i = 0; i < 2; ++i) {
        const int kk = kk0 + i * 8;
        union { unsigned short u[8]; uint4 q; } pk;
#pragma unroll
        for (int j = 0; j < 8; ++j) pk.u[j] = bfb(ls[kk + j][h]);
        *(uint4*)(WT + (size_t)(wsel * 64 + h) * EMB + k0 + kk) = pk.q;
    }
}

// ---------------------------------------------------------------------------
// gemm_proj v4 (unchanged from R7, ~34 us): async DMA staging, XOR swizzle.
// ---------------------------------------------------------------------------
__global__ __launch_bounds__(256) void gemm_proj(
    const float* __restrict__ x,
    const __hip_bfloat16* __restrict__ WT,
    __hip_bfloat16* __restrict__ qs,
    __hip_bfloat16* __restrict__ kb,
    __hip_bfloat16* __restrict__ vT)
{
    __shared__ __align__(16) char sm[8 * 1040 + 24 * 1040];   // 33,280 B
    char* smA = sm;
    char* smB = sm + 8 * 1040;

    const int tid  = threadIdx.x;
    const int lane = tid & 63;
    const int c    = lane & 15;
    const int quad = lane >> 4;
    const int w    = tid >> 6;
    const int rw   = w & 1;
    const int nh   = w >> 1;
    const int R0   = blockIdx.x * 32;

    const int rrA = lane >> 4;
    const int ciA = (lane & 15) ^ (rrA << 1);
    const int rrB = lane >> 3;
    const int ciB = (lane & 7) ^ rrB;

    const int rA  = rw * 16 + c;
    const int gA  = rA >> 2;
    const int rrr = rA & 3;
    const char* paBase = smA + gA * 1040 + rrr * 256;

    f32x4 acc[6];
#pragma unroll
    for (int f = 0; f < 6; ++f) acc[f] = (f32x4){0.f, 0.f, 0.f, 0.f};

    for (int s = 0; s < 16; ++s) {
        const int k0 = s * 64;
#pragma unroll
        for (int j = 0; j < 2; ++j) {
            const int g = w * 2 + j;
            const float* ga = x + (size_t)(R0 + g * 4 + rrA) * EMB + k0 + ciA * 4;
            gld16(ga, smA + g * 1040);
        }
#pragma unroll
        for (int j = 0; j < 6; ++j) {
            const int gb = w * 6 + j;
            const __hip_bfloat16* gw = WT + (size_t)(gb * 8 + rrB) * EMB + k0 + ciB * 8;
            gld16(gw, smB + gb * 1040);
        }
        __syncthreads();

#pragma unroll
        for (int ks = 0; ks < 2; ++ks) {
            const int ci0 = ks * 8 + quad * 2;
            const int ps0 = ci0 ^ (rrr << 1);
            const char* pa = paBase + ps0 * 16;
            const float4 fa = *(const float4*)pa;
            const float4 fb = *(const float4*)(pa + 16);
            union { unsigned short u[8]; short8 s8; } av;
            av.u[0] = bfb(fa.x); av.u[1] = bfb(fa.y);
            av.u[2] = bfb(fa.z); av.u[3] = bfb(fa.w);
            av.u[4] = bfb(fb.x); av.u[5] = bfb(fb.y);
            av.u[6] = bfb(fb.z); av.u[7] = bfb(fb.w);
#pragma unroll
            for (int f = 0; f < 6; ++f) {
                const int n   = nh * 96 + f * 16 + c;
                const int gB  = n >> 3;
                const int rB  = n & 7;
                const int psb = (ks * 4 + quad) ^ rB;
                const short8 bfrag = ld8l(smB + gB * 1040 + rB * 128 + psb * 16);
                acc[f] = __builtin_amdgcn_mfma_f32_16x16x32_bf16(av.s8, bfrag, acc[f], 0, 0, 0);
            }
        }
        __syncthreads();
    }

#pragma unroll
    for (int f = 0; f < 6; ++f) {
#pragma unroll
        for (int r = 0; r < 4; ++r) {
            const int m = R0 + rw * 16 + quad * 4 + r;
            const int n = nh * 96 + f * 16 + c;
            const float val = acc[f][r];
            if (n < 64) {
                qs[(size_t)m * HD + n] = __hip_bfloat16(val * SCALE);
            } else if (n < 128) {
                kb[(size_t)m * HD + (n - 64)] = __hip_bfloat16(val);
            } else {
                const int b  = m >> 12;
                const int sq = m & (SEQ - 1);
                const int sp = (sq & ~63) | ((sq & 15) << 2) | ((sq >> 4) & 3);
                vT[((size_t)b * HD + (n - 128)) * SEQ + sp] = __hip_bfloat16(val);
            }
        }
    }
}

// ---------------------------------------------------------------------------
// attn v3: cooperative DMA-staged K/V, 4 waves x 16 Q rows = 64-row Q tile.
// Per 64-key tile: block stages K(8KB)+V(8KB) via global_load_lds with XOR
// swizzle (2-way reads = free); each wave computes QK->exp->P->PV for its
// own rows (no intra-block combine). Split-K: 4 stripes across blocks;
// partial (o,l) accumulated with fp32 atomicAdd into out/lacc (max-free
// softmax => additive). Generation-mirrored map balances ~33 tiles/CU.
// LDS 25.6 KB -> 4 blocks/CU resident.
// ---------------------------------------------------------------------------
__global__ __launch_bounds__(256) void attn_kernel(
    const __hip_bfloat16* __restrict__ qs,
    const __hip_bfloat16* __restrict__ kmat,
    const __hip_bfloat16* __restrict__ vT,
    float* __restrict__ outacc,
    float* __restrict__ lacc)
{
    __shared__ __align__(16) char smK[64 * 128];   // [key][dim], swizzled
    __shared__ __align__(16) char smV[64 * 128];   // [dim][keypos], swizzled
    __shared__ unsigned int Ps[4][16 * 36];        // per-wave P buffers

    const int tid  = threadIdx.x;
    const int w    = tid >> 6;
    const int lane = tid & 63;
    const int c    = lane & 15;
    const int quad = lane >> 4;

    const int g      = blockIdx.x;       // 0..1023
    const int gen    = g >> 8;           // generation = stripe
    const int jj     = g & 255;
    const int b      = jj & 3;
    const int r_     = jj >> 2;          // 0..63
    const int t      = (gen & 1) ? r_ : 63 - r_;   // mirrored across gens
    const int stripe = gen;
    const int q0w    = t * 64 + w * 16;  // this wave's first Q row

    const __hip_bfloat16* kbb = kmat + (size_t)b * SEQ * HD;
    const __hip_bfloat16* vTb = vT + (size_t)b * HD * SEQ;

    const __hip_bfloat16* qp = qs + ((size_t)b * SEQ + q0w + c) * HD + quad * 8;
    const short8 aq0 = ld8g(qp);
    const short8 aq1 = ld8g(qp + 32);

    // DMA lane invariants: row-in-group + XOR-swizzled chunk
    const int rr = lane >> 3;            // 0..7
    const int ci = (lane & 7) ^ rr;      // global 16B chunk for stored pos

    f32x4 o0 = {0.f,0.f,0.f,0.f}, o1 = o0, o2 = o0, o3 = o0;
    f32x4 lp = {0.f,0.f,0.f,0.f};
    const f32x4 z = {0.f,0.f,0.f,0.f};

    for (int T = stripe; T <= t; T += NSTRIPE) {
        const int k0 = T << 6;

        // ---- stage K and V tiles (async DMA, all 4 waves) ----
#pragma unroll
        for (int j = 0; j < 2; ++j) {
            const int grp = w * 2 + j;           // 0..7, 8 rows each
            const int row = grp * 8 + rr;
            gld16(kbb + (size_t)(k0 + row) * HD + ci * 8, smK + grp * 1024);
            gld16(vTb + (size_t)row * SEQ + k0 + ci * 8, smV + grp * 1024);
        }
        __syncthreads();                 // drains DMA + barrier

        // ---- QK^T: B-frags from swizzled K tile ----
        f32x4 sf[4];
#pragma unroll
        for (int f = 0; f < 4; ++f) {
            const int kr = f * 16 + c;
            const char* kp = smK + kr * 128;
            const short8 bk0 = ld8l(kp + ((quad    ) ^ (kr & 7)) * 16);
            const short8 bk1 = ld8l(kp + ((quad + 4) ^ (kr & 7)) * 16);
            sf[f] = __builtin_amdgcn_mfma_f32_16x16x32_bf16(aq0, bk0, z, 0, 0, 0);
            sf[f] = __builtin_amdgcn_mfma_f32_16x16x32_bf16(aq1, bk1, sf[f], 0, 0, 0);
        }

        if (T == t) {                    // diagonal tile: causal mask
#pragma unroll
            for (int f = 0; f < 4; ++f) {
                const int key = k0 + f * 16 + c;
#pragma unroll
                for (int r = 0; r < 4; ++r)
                    if (key > q0w + quad * 4 + r) sf[f][r] = -1e30f;
            }
        }

        // ---- p = exp(s); l partials; pack P (permuted cols) ----
        float p[4][4];
#pragma unroll
        for (int f = 0; f < 4; ++f)
#pragma unroll
            for (int r = 0; r < 4; ++r)
                p[f][r] = __expf(sf[f][r]);
#pragma unroll
        for (int r = 0; r < 4; ++r) {
            lp[r] += (p[0][r] + p[1][r]) + (p[2][r] + p[3][r]);
            uint2 dd;
            dd.x = (unsigned int)bfb(p[0][r]) | ((unsigned int)bfb(p[1][r]) << 16);
            dd.y = (unsigned int)bfb(p[2][r]) | ((unsigned int)bfb(p[3][r]) << 16);
            *(uint2*)&Ps[w][(quad * 4 + r) * 36 + c * 2] = dd;   // pos = c*4+f
        }

        const short8 ap0 = ld8l(&Ps[w][c * 36 + quad * 4]);
        const short8 ap1 = ld8l(&Ps[w][c * 36 + 16 + quad * 4]);

        // ---- PV: B-frags from swizzled V tile (keypos-permuted) ----
        {
            const int vr = 0 * 16 + c;
            const char* vp = smV + vr * 128;
            const short8 bv0 = ld8l(vp + ((quad    ) ^ (vr & 7)) * 16);
            const short8 bv1 = ld8l(vp + ((quad + 4) ^ (vr & 7)) * 16);
            o0 = __builtin_amdgcn_mfma_f32_16x16x32_bf16(ap0, bv0, o0, 0, 0, 0);
            o0 = __builtin_amdgcn_mfma_f32_16x16x32_bf16(ap1, bv1, o0, 0, 0, 0);
        }
        {
            const int vr = 1 * 16 + c;
            const char* vp = smV + vr * 128;
            const short8 bv0 = ld8l(vp + ((quad    ) ^ (vr & 7)) * 16);
            const short8 bv1 = ld8l(vp + ((quad + 4) ^ (vr & 7)) * 16);
            o1 = __builtin_amdgcn_mfma_f32_16x16x32_bf16(ap0, bv0, o1, 0, 0, 0);
            o1 = __builtin_amdgcn_mfma_f32_16x16x32_bf16(ap1, bv1, o1, 0, 0, 0);
        }
        {
            const int vr = 2 * 16 + c;
            const char* vp = smV + vr * 128;
            const short8 bv0 = ld8l(vp + ((quad    ) ^ (vr & 7)) * 16);
            const short8 bv1 = ld8l(vp + ((quad + 4) ^ (vr & 7)) * 16);
            o2 = __builtin_amdgcn_mfma_f32_16x16x32_bf16(ap0, bv0, o2, 0, 0, 0);
            o2 = __builtin_amdgcn_mfma_f32_16x16x32_bf16(ap1, bv1, o2, 0, 0, 0);
        }
        {
            const int vr = 3 * 16 + c;
            const char* vp = smV + vr * 128;
            const short8 bv0 = ld8l(vp + ((quad    ) ^ (vr & 7)) * 16);
            const short8 bv1 = ld8l(vp + ((quad + 4) ^ (vr & 7)) * 16);
            o3 = __builtin_amdgcn_mfma_f32_16x16x32_bf16(ap0, bv0, o3, 0, 0, 0);
            o3 = __builtin_amdgcn_mfma_f32_16x16x32_bf16(ap1, bv1, o3, 0, 0, 0);
        }
        __syncthreads();                 // all LDS reads done before restage
    }

    // ---- l reduction across the 16 cols ----
#pragma unroll
    for (int r = 0; r < 4; ++r) {
        float v = lp[r];
        v += __shfl_xor(v, 1, 64);
        v += __shfl_xor(v, 2, 64);
        v += __shfl_xor(v, 4, 64);
        v += __shfl_xor(v, 8, 64);
        lp[r] = v;
    }

    // ---- accumulate partials: fp32 atomics (additive across stripes) ----
    float* ob = outacc + ((size_t)b * SEQ + q0w) * HD;
#pragma unroll
    for (int r = 0; r < 4; ++r) {
        const int row = quad * 4 + r;
        atomicAdd(&ob[row * HD +  0 + c], o0[r]);
        atomicAdd(&ob[row * HD + 16 + c], o1[r]);
        atomicAdd(&ob[row * HD + 32 + c], o2[r]);
        atomicAdd(&ob[row * HD + 48 + c], o3[r]);
        if (c == 0) atomicAdd(&lacc[(size_t)b * SEQ + q0w + row], lp[r]);
    }
}

// ---------------------------------------------------------------------------
// normalize: out[i] = sum_o / sum_l
// ---------------------------------------------------------------------------
__global__ __launch_bounds__(256) void normalize_kernel(
    float* __restrict__ out, const float* __restrict__ lacc)
{
    const int idx = blockIdx.x * 256 + threadIdx.x;
    out[idx] /= lacc[idx >> 6];
}

// ---------------------------------------------------------------------------
extern "C" void kernel_launch(void* const* d_in, const int* in_sizes, int n_in,
                              void* d_out, int out_size, void* d_ws, size_t ws_size,
                              hipStream_t stream)
{
    (void)in_sizes; (void)n_in; (void)out_size; (void)ws_size;
    const float* x  = (const float*)d_in[0];
    const float* Wk = (const float*)d_in[1];
    const float* Wq = (const float*)d_in[2];
    const float* Wv = (const float*)d_in[3];
    float* out = (float*)d_out;

    const size_t BSH = (size_t)BATCH * SEQ * HD;        // 1,048,576 elems
    __hip_bfloat16* qs = (__hip_bfloat16*)d_ws;         // 2 MB
    __hip_bfloat16* kb = qs + BSH;                      // 2 MB
    __hip_bfloat16* vT = kb + BSH;                      // 2 MB
    __hip_bfloat16* WT = vT + BSH;                      // 384 KB
    float* lacc = (float*)(WT + 192 * EMB);             // 64 KB (~6.5 MB ws)

    prep_w<<<48, 256, 0, stream>>>(Wk, Wq, Wv, WT);
    gemm_proj<<<BATCH * SEQ / 32, 256, 0, stream>>>(x, WT, qs, kb, vT);
    hipMemsetAsync(out, 0, BSH * sizeof(float), stream);
    hipMemsetAsync(lacc, 0, (size_t)BATCH * SEQ * sizeof(float), stream);
    attn_kernel<<<NSTRIPE * BATCH * (SEQ / 64), 256, 0, stream>>>(qs, kb, vT, out, lacc);
    normalize_kernel<<<BATCH * SEQ * HD / 256, 256, 0, stream>>>(out, lacc);
}

// Round 9
// 144.624 us; speedup vs baseline: 1.4652x; 1.0250x over previous
//
#include <hip/hip_runtime.h>
#include <hip/hip_bf16.h>
#include <math.h>

#define BATCH 4
#define SEQ   4096
#define EMB   1024
#define HD    64
#define SCALE 0.03125f   // EMB^-0.5 = 1/32, exact in bf16
#define NSTRIPE 4

typedef __attribute__((ext_vector_type(8))) short short8;  // 8 bf16 = 4 VGPRs
typedef __attribute__((ext_vector_type(4))) float f32x4;

__device__ __forceinline__ short8 ld8g(const __hip_bfloat16* p) {
    union { uint4 u; short8 s; } cv;
    cv.u = *(const uint4*)p;
    return cv.s;
}
__device__ __forceinline__ short8 ld8l(const void* p) {
    union { uint4 u; short8 s; } cv;
    cv.u = *(const uint4*)p;
    return cv.s;
}
__device__ __forceinline__ unsigned short bfb(float a) {
    union { __hip_bfloat16 h; unsigned short u; } cv;
    cv.h = __hip_bfloat16(a);
    return cv.u;
}

// async global->LDS DMA, 16 B/lane. LDS dest = wave-uniform base + lane*16.
__device__ __forceinline__ void gld16(const void* g, const void* lds_base) {
    __builtin_amdgcn_global_load_lds(
        (const __attribute__((address_space(1))) void*)(unsigned long long)(uintptr_t)g,
        (__attribute__((address_space(3))) void*)(unsigned)(uintptr_t)lds_base,
        16, 0, 0);
}

// ---------------------------------------------------------------------------
// prep_w v2: coalesced transpose via LDS (unchanged from R8, ~3 us).
// ---------------------------------------------------------------------------
__global__ __launch_bounds__(256) void prep_w(
    const float* __restrict__ Wk, const float* __restrict__ Wq,
    const float* __restrict__ Wv, __hip_bfloat16* __restrict__ WT)
{
    __shared__ float ls[64][65];
    const int wsel = blockIdx.x >> 4;
    const int kblk = blockIdx.x & 15;
    const int k0   = kblk * 64;
    const float* W = (wsel == 0) ? Wq : (wsel == 1) ? Wk : Wv;
    const int t = threadIdx.x;
#pragma unroll
    for (int i = 0; i < 4; ++i) {
        const int idx = t + i * 256;
        const int row = idx >> 4;
        const int c4  = idx & 15;
        const float4 v = *(const float4*)(W + (size_t)(k0 + row) * HD + c4 * 4);
        ls[row][c4 * 4 + 0] = v.x; ls[row][c4 * 4 + 1] = v.y;
        ls[row][c4 * 4 + 2] = v.z; ls[row][c4 * 4 + 3] = v.w;
    }
    __syncthreads();
    const int h   = t >> 2;
    const int kk0 = (t & 3) * 16;
#pragma unroll
    for (int i = 0; i < 2; ++i) {
        const int kk = kk0 + i * 8;
        union { unsigned short u[8]; uint4 q; } pk;
#pragma unroll
        for (int j = 0; j < 8; ++j) pk.u[j] = bfb(ls[kk + j][h]);
        *(uint4*)(WT + (size_t)(wsel * 64 + h) * EMB + k0 + kk) = pk.q;
    }
}

// ---------------------------------------------------------------------------
// gemm_proj v5: R7 structure + DOUBLE-BUFFERED DMA staging. One barrier per
// K-step; tile s+1's DMA (issued right after the barrier) overlaps compute
// of tile s instead of being drained cold at the next barrier.
// LDS 2 x 33,280 B; 512 blocks, 2 blocks/CU.
// ---------------------------------------------------------------------------
__global__ __launch_bounds__(256) void gemm_proj(
    const float* __restrict__ x,
    const __hip_bfloat16* __restrict__ WT,
    __hip_bfloat16* __restrict__ qs,
    __hip_bfloat16* __restrict__ kb,
    __hip_bfloat16* __restrict__ vT)
{
    __shared__ __align__(16) char sm[2][8 * 1040 + 24 * 1040];   // 2 x 33,280 B

    const int tid  = threadIdx.x;
    const int lane = tid & 63;
    const int c    = lane & 15;
    const int quad = lane >> 4;
    const int w    = tid >> 6;
    const int rw   = w & 1;
    const int nh   = w >> 1;
    const int R0   = blockIdx.x * 32;

    const int rrA = lane >> 4;
    const int ciA = (lane & 15) ^ (rrA << 1);
    const int rrB = lane >> 3;
    const int ciB = (lane & 7) ^ rrB;

    const int rA  = rw * 16 + c;
    const int gA  = rA >> 2;
    const int rrr = rA & 3;

    f32x4 acc[6];
#pragma unroll
    for (int f = 0; f < 6; ++f) acc[f] = (f32x4){0.f, 0.f, 0.f, 0.f};

    // ---- stage helper (expanded inline twice below) ----
#define STAGE(buf, kk)                                                          \
    do {                                                                        \
        char* sA = sm[buf];                                                     \
        char* sB = sm[buf] + 8 * 1040;                                          \
        _Pragma("unroll")                                                       \
        for (int j = 0; j < 2; ++j) {                                           \
            const int g = w * 2 + j;                                            \
            gld16(x + (size_t)(R0 + g * 4 + rrA) * EMB + (kk) + ciA * 4,        \
                  sA + g * 1040);                                               \
        }                                                                       \
        _Pragma("unroll")                                                       \
        for (int j = 0; j < 6; ++j) {                                           \
            const int gb = w * 6 + j;                                           \
            gld16(WT + (size_t)(gb * 8 + rrB) * EMB + (kk) + ciB * 8,           \
                  sB + gb * 1040);                                              \
        }                                                                       \
    } while (0)

    STAGE(0, 0);
    __syncthreads();                       // buf0 ready

    for (int s = 0; s < 16; ++s) {
        const int cur = s & 1, nxt = cur ^ 1;
        if (s < 15) STAGE(nxt, (s + 1) * 64);   // overlaps compute below

        const char* smA = sm[cur];
        const char* smB = sm[cur] + 8 * 1040;
        const char* paBase = smA + gA * 1040 + rrr * 256;
#pragma unroll
        for (int ks = 0; ks < 2; ++ks) {
            const int ci0 = ks * 8 + quad * 2;
            const int ps0 = ci0 ^ (rrr << 1);
            const char* pa = paBase + ps0 * 16;
            const float4 fa = *(const float4*)pa;
            const float4 fb = *(const float4*)(pa + 16);
            union { unsigned short u[8]; short8 s8; } av;
            av.u[0] = bfb(fa.x); av.u[1] = bfb(fa.y);
            av.u[2] = bfb(fa.z); av.u[3] = bfb(fa.w);
            av.u[4] = bfb(fb.x); av.u[5] = bfb(fb.y);
            av.u[6] = bfb(fb.z); av.u[7] = bfb(fb.w);
#pragma unroll
            for (int f = 0; f < 6; ++f) {
                const int n   = nh * 96 + f * 16 + c;
                const int gB  = n >> 3;
                const int rB  = n & 7;
                const int psb = (ks * 4 + quad) ^ rB;
                const short8 bfrag = ld8l(smB + gB * 1040 + rB * 128 + psb * 16);
                acc[f] = __builtin_amdgcn_mfma_f32_16x16x32_bf16(av.s8, bfrag, acc[f], 0, 0, 0);
            }
        }
        __syncthreads();                   // drains nxt DMA + frees cur
    }
#undef STAGE

#pragma unroll
    for (int f = 0; f < 6; ++f) {
#pragma unroll
        for (int r = 0; r < 4; ++r) {
            const int m = R0 + rw * 16 + quad * 4 + r;
            const int n = nh * 96 + f * 16 + c;
            const float val = acc[f][r];
            if (n < 64) {
                qs[(size_t)m * HD + n] = __hip_bfloat16(val * SCALE);
            } else if (n < 128) {
                kb[(size_t)m * HD + (n - 64)] = __hip_bfloat16(val);
            } else {
                const int b  = m >> 12;
                const int sq = m & (SEQ - 1);
                const int sp = (sq & ~63) | ((sq & 15) << 2) | ((sq >> 4) & 3);
                vT[((size_t)b * HD + (n - 128)) * SEQ + sp] = __hip_bfloat16(val);
            }
        }
    }
}

// ---------------------------------------------------------------------------
// attn v4: R8 structure, atomics ELIMINATED (R8 post-mortem: 4.2M device-
// scope atomicAdds with 4-way cross-XCD contention ~27 us tail). Each stripe
// writes private partial (O,l) buffers with plain stores; blocks with no
// tiles write zeros, so no zero-init pass needed. normalize sums stripes.
// ---------------------------------------------------------------------------
__global__ __launch_bounds__(256) void attn_kernel(
    const __hip_bfloat16* __restrict__ qs,
    const __hip_bfloat16* __restrict__ kmat,
    const __hip_bfloat16* __restrict__ vT,
    float* __restrict__ Opart,     // [NSTRIPE][BATCH*SEQ*HD]
    float* __restrict__ Lpart)     // [NSTRIPE][BATCH*SEQ]
{
    __shared__ __align__(16) char smK[64 * 128];
    __shared__ __align__(16) char smV[64 * 128];
    __shared__ unsigned int Ps[4][16 * 36];

    const int tid  = threadIdx.x;
    const int w    = tid >> 6;
    const int lane = tid & 63;
    const int c    = lane & 15;
    const int quad = lane >> 4;

    const int g      = blockIdx.x;       // 0..1023
    const int gen    = g >> 8;           // generation = stripe
    const int jj     = g & 255;
    const int b      = jj & 3;
    const int r_     = jj >> 2;          // 0..63
    const int t      = (gen & 1) ? r_ : 63 - r_;
    const int stripe = gen;
    const int q0w    = t * 64 + w * 16;

    const __hip_bfloat16* kbb = kmat + (size_t)b * SEQ * HD;
    const __hip_bfloat16* vTb = vT + (size_t)b * HD * SEQ;

    const __hip_bfloat16* qp = qs + ((size_t)b * SEQ + q0w + c) * HD + quad * 8;
    const short8 aq0 = ld8g(qp);
    const short8 aq1 = ld8g(qp + 32);

    const int rr = lane >> 3;
    const int ci = (lane & 7) ^ rr;

    f32x4 o0 = {0.f,0.f,0.f,0.f}, o1 = o0, o2 = o0, o3 = o0;
    f32x4 lp = {0.f,0.f,0.f,0.f};
    const f32x4 z = {0.f,0.f,0.f,0.f};

    for (int T = stripe; T <= t; T += NSTRIPE) {
        const int k0 = T << 6;

#pragma unroll
        for (int j = 0; j < 2; ++j) {
            const int grp = w * 2 + j;
            const int row = grp * 8 + rr;
            gld16(kbb + (size_t)(k0 + row) * HD + ci * 8, smK + grp * 1024);
            gld16(vTb + (size_t)row * SEQ + k0 + ci * 8, smV + grp * 1024);
        }
        __syncthreads();

        f32x4 sf[4];
#pragma unroll
        for (int f = 0; f < 4; ++f) {
            const int kr = f * 16 + c;
            const char* kp = smK + kr * 128;
            const short8 bk0 = ld8l(kp + ((quad    ) ^ (kr & 7)) * 16);
            const short8 bk1 = ld8l(kp + ((quad + 4) ^ (kr & 7)) * 16);
            sf[f] = __builtin_amdgcn_mfma_f32_16x16x32_bf16(aq0, bk0, z, 0, 0, 0);
            sf[f] = __builtin_amdgcn_mfma_f32_16x16x32_bf16(aq1, bk1, sf[f], 0, 0, 0);
        }

        if (T == t) {
#pragma unroll
            for (int f = 0; f < 4; ++f) {
                const int key = k0 + f * 16 + c;
#pragma unroll
                for (int r = 0; r < 4; ++r)
                    if (key > q0w + quad * 4 + r) sf[f][r] = -1e30f;
            }
        }

        float p[4][4];
#pragma unroll
        for (int f = 0; f < 4; ++f)
#pragma unroll
            for (int r = 0; r < 4; ++r)
                p[f][r] = __expf(sf[f][r]);
#pragma unroll
        for (int r = 0; r < 4; ++r) {
            lp[r] += (p[0][r] + p[1][r]) + (p[2][r] + p[3][r]);
            uint2 dd;
            dd.x = (unsigned int)bfb(p[0][r]) | ((unsigned int)bfb(p[1][r]) << 16);
            dd.y = (unsigned int)bfb(p[2][r]) | ((unsigned int)bfb(p[3][r]) << 16);
            *(uint2*)&Ps[w][(quad * 4 + r) * 36 + c * 2] = dd;
        }

        const short8 ap0 = ld8l(&Ps[w][c * 36 + quad * 4]);
        const short8 ap1 = ld8l(&Ps[w][c * 36 + 16 + quad * 4]);

#pragma unroll
        for (int f = 0; f < 4; ++f) {
            const int vr = f * 16 + c;
            const char* vp = smV + vr * 128;
            const short8 bv0 = ld8l(vp + ((quad    ) ^ (vr & 7)) * 16);
            const short8 bv1 = ld8l(vp + ((quad + 4) ^ (vr & 7)) * 16);
            f32x4* po = (f == 0) ? &o0 : (f == 1) ? &o1 : (f == 2) ? &o2 : &o3;
            *po = __builtin_amdgcn_mfma_f32_16x16x32_bf16(ap0, bv0, *po, 0, 0, 0);
            *po = __builtin_amdgcn_mfma_f32_16x16x32_bf16(ap1, bv1, *po, 0, 0, 0);
        }
        __syncthreads();
    }

#pragma unroll
    for (int r = 0; r < 4; ++r) {
        float v = lp[r];
        v += __shfl_xor(v, 1, 64);
        v += __shfl_xor(v, 2, 64);
        v += __shfl_xor(v, 4, 64);
        v += __shfl_xor(v, 8, 64);
        lp[r] = v;
    }

    // ---- plain stores of stripe-private partials (zeros if no tiles) ----
    float* ob = Opart + (size_t)stripe * (BATCH * SEQ * HD)
                      + ((size_t)b * SEQ + q0w) * HD;
#pragma unroll
    for (int r = 0; r < 4; ++r) {
        const int row = quad * 4 + r;
        ob[row * HD +  0 + c] = o0[r];
        ob[row * HD + 16 + c] = o1[r];
        ob[row * HD + 32 + c] = o2[r];
        ob[row * HD + 48 + c] = o3[r];
        if (c == 0)
            Lpart[(size_t)stripe * (BATCH * SEQ) + (size_t)b * SEQ + q0w + row] = lp[r];
    }
}

// ---------------------------------------------------------------------------
// normalize v2: out = (sum_s Opart[s]) / (sum_s Lpart[s]), float4-vectorized.
// ---------------------------------------------------------------------------
__global__ __launch_bounds__(256) void normalize_kernel(
    float* __restrict__ out,
    const float* __restrict__ Opart,
    const float* __restrict__ Lpart)
{
    const int idx4 = blockIdx.x * 256 + threadIdx.x;   // 0..262143 (float4s)
    const int row  = idx4 >> 4;                        // 16 float4 per row
    const float4* O4 = (const float4*)Opart;
    float4 s = O4[idx4];
    float  l = Lpart[row];
#pragma unroll
    for (int st = 1; st < NSTRIPE; ++st) {
        const float4 v = O4[(size_t)st * (BATCH * SEQ * HD / 4) + idx4];
        s.x += v.x; s.y += v.y; s.z += v.z; s.w += v.w;
        l += Lpart[(size_t)st * (BATCH * SEQ) + row];
    }
    const float inv = 1.0f / l;
    float4 o; o.x = s.x * inv; o.y = s.y * inv; o.z = s.z * inv; o.w = s.w * inv;
    ((float4*)out)[idx4] = o;
}

// ---------------------------------------------------------------------------
extern "C" void kernel_launch(void* const* d_in, const int* in_sizes, int n_in,
                              void* d_out, int out_size, void* d_ws, size_t ws_size,
                              hipStream_t stream)
{
    (void)in_sizes; (void)n_in; (void)out_size; (void)ws_size;
    const float* x  = (const float*)d_in[0];
    const float* Wk = (const float*)d_in[1];
    const float* Wq = (const float*)d_in[2];
    const float* Wv = (const float*)d_in[3];
    float* out = (float*)d_out;

    const size_t BSH = (size_t)BATCH * SEQ * HD;        // 1,048,576 elems
    __hip_bfloat16* qs = (__hip_bfloat16*)d_ws;         // 2 MB
    __hip_bfloat16* kb = qs + BSH;                      // 2 MB
    __hip_bfloat16* vT = kb + BSH;                      // 2 MB
    __hip_bfloat16* WT = vT + BSH;                      // 384 KB
    float* Opart = (float*)(WT + 192 * EMB);            // 16 MB (4 stripes)
    float* Lpart = Opart + (size_t)NSTRIPE * BSH;       // 256 KB  (~23 MB ws)

    prep_w<<<48, 256, 0, stream>>>(Wk, Wq, Wv, WT);
    gemm_proj<<<BATCH * SEQ / 32, 256, 0, stream>>>(x, WT, qs, kb, vT);
    attn_kernel<<<NSTRIPE * BATCH * (SEQ / 64), 256, 0, stream>>>(qs, kb, vT, Opart, Lpart);
    normalize_kernel<<<BATCH * SEQ * HD / 4 / 256, 256, 0, stream>>>(out, Opart, Lpart);
}